// Round 5
// baseline (303.692 us; speedup 1.0000x reference)
//
#include <hip/hip_runtime.h>
#include <hip/hip_bf16.h>

#define B_     32
#define C_     256
#define T_     4096
#define NH_    8
#define DH_    64

// ---------------------------------------------------------------------------
// K1: fold q-projection into Wkv_k.
//   qW[b,c,n] = scale * sum_d q[b,n,d] * Wkv[n*64+d, c]
//   qb[b,n]   = scale * sum_d q[b,n,d] * bkv[n*64+d]
// grid (NH_, B_) = 256 blocks, block 256.
// ---------------------------------------------------------------------------
__global__ __launch_bounds__(256) void k_prep(
    const float* __restrict__ query, const float* __restrict__ Wkv,
    const float* __restrict__ bkv, const float* __restrict__ Wq,
    const float* __restrict__ bq, float* __restrict__ qWt,
    float* __restrict__ qb) {
  const int n = blockIdx.x;
  const int b = blockIdx.y;
  const int t = threadIdx.x;
  __shared__ float qrow_s[C_];
  __shared__ float psum[4 * 64];
  __shared__ float qsh[64];
  __shared__ float pb_s[64];

  qrow_s[t] = query[(size_t)b * C_ + t];
  __syncthreads();

  {
    const int d = t & 63, ch = t >> 6;
    const float* wrow = Wq + (size_t)(n * DH_ + d) * C_ + ch * 64;
    const float* qr = qrow_s + ch * 64;
    float s = 0.f;
    #pragma unroll
    for (int c = 0; c < 64; c += 4) {
      float4 w = *(const float4*)(wrow + c);
      s += w.x * qr[c] + w.y * qr[c + 1] + w.z * qr[c + 2] + w.w * qr[c + 3];
    }
    psum[ch * 64 + d] = s;
  }
  __syncthreads();
  if (t < 64)
    qsh[t] = bq[n * DH_ + t] + psum[t] + psum[64 + t] + psum[128 + t] + psum[192 + t];
  __syncthreads();

  const float scale = 0.125f;
  {
    const float* wk = Wkv + (size_t)(n * DH_) * C_ + t;
    float acc = 0.f;
    #pragma unroll 8
    for (int dd = 0; dd < DH_; ++dd) acc += qsh[dd] * wk[(size_t)dd * C_];
    qWt[((size_t)b * C_ + t) * NH_ + n] = acc * scale;
  }
  if (t < 64) pb_s[t] = qsh[t] * bkv[n * DH_ + t];
  __syncthreads();
  if (t == 0) {
    float s = 0.f;
    #pragma unroll 8
    for (int dd = 0; dd < 64; ++dd) s += pb_s[dd];
    qb[b * NH_ + n] = s * scale;
  }
}

// ---------------------------------------------------------------------------
// K2: partial logits over a c-half:
//   lgpart[half,b,n,j] = sum_{c in half} qW[b,c,n] * x[b,c,j]  (+qb if half 0)
// grid (8, 2, B_) = 512 blocks, block 128, 4 j/thread (float4 = 16B/lane),
// 8-deep load prefetch.
// ---------------------------------------------------------------------------
__global__ __launch_bounds__(128) void k_logits(
    const float* __restrict__ x, const float* __restrict__ qWt,
    const float* __restrict__ qbv, float* __restrict__ lgpart) {
  const int half = blockIdx.y;
  const int b = blockIdx.z;
  const int t = threadIdx.x;            // 0..127
  const int j = blockIdx.x * 512 + t * 4;
  __shared__ float qws[128 * NH_];      // 4 KB, [c_local][n]

  {
    const float* src = qWt + (size_t)b * (C_ * NH_) + half * 1024;
    *(float4*)(qws + t * 8)     = *(const float4*)(src + t * 8);
    *(float4*)(qws + t * 8 + 4) = *(const float4*)(src + t * 8 + 4);
  }
  __syncthreads();

  const float* xb = x + ((size_t)b * C_ + half * 128) * T_ + j;
  const float* qb = qbv + b * NH_;

  float4 acc[NH_];
  #pragma unroll
  for (int n = 0; n < NH_; ++n) {
    const float init = half ? 0.f : qb[n];
    acc[n].x = init; acc[n].y = init; acc[n].z = init; acc[n].w = init;
  }

#define FMA8_(W, A) { A.x += (W) * xv4.x; A.y += (W) * xv4.y; \
                      A.z += (W) * xv4.z; A.w += (W) * xv4.w; }
  for (int c0 = 0; c0 < 128; c0 += 8) {
    float4 xv[8];
    #pragma unroll
    for (int cc = 0; cc < 8; ++cc)
      xv[cc] = *(const float4*)(xb + (size_t)(c0 + cc) * T_);
    #pragma unroll
    for (int cc = 0; cc < 8; ++cc) {
      const float4 w0 = *(const float4*)(qws + (c0 + cc) * 8);
      const float4 w1 = *(const float4*)(qws + (c0 + cc) * 8 + 4);
      const float4 xv4 = xv[cc];
      FMA8_(w0.x, acc[0]); FMA8_(w0.y, acc[1]);
      FMA8_(w0.z, acc[2]); FMA8_(w0.w, acc[3]);
      FMA8_(w1.x, acc[4]); FMA8_(w1.y, acc[5]);
      FMA8_(w1.z, acc[6]); FMA8_(w1.w, acc[7]);
    }
  }
#undef FMA8_

  float* lg = lgpart + (((size_t)half * B_ + b) * NH_) * T_ + j;
  #pragma unroll
  for (int n = 0; n < NH_; ++n)
    *(float4*)(lg + (size_t)n * T_) = acc[n];
}

// ---------------------------------------------------------------------------
// K3: attn[row,j] = softmax_j(lg0[row,j] + lg1[row,j]); grid 256, block 256.
// ---------------------------------------------------------------------------
__global__ __launch_bounds__(256) void k_softmax(
    const float* __restrict__ lgpart, float* __restrict__ attn) {
  const size_t row = blockIdx.x;  // b*NH + n
  const float* p0 = lgpart + row * T_;
  const float* p1 = lgpart + ((size_t)B_ * NH_ + row) * T_;
  float* pa = attn + row * T_;
  const int t = threadIdx.x;
  float4 v[4];
  #pragma unroll
  for (int i = 0; i < 4; ++i) {
    float4 a = *(const float4*)(p0 + t * 4 + i * 1024);
    float4 c = *(const float4*)(p1 + t * 4 + i * 1024);
    v[i].x = a.x + c.x; v[i].y = a.y + c.y; v[i].z = a.z + c.z; v[i].w = a.w + c.w;
  }

  float m = -3.4e38f;
  #pragma unroll
  for (int i = 0; i < 4; ++i)
    m = fmaxf(m, fmaxf(fmaxf(v[i].x, v[i].y), fmaxf(v[i].z, v[i].w)));
  #pragma unroll
  for (int o = 32; o >= 1; o >>= 1) m = fmaxf(m, __shfl_xor(m, o));
  __shared__ float sm[4];
  if ((t & 63) == 0) sm[t >> 6] = m;
  __syncthreads();
  m = fmaxf(fmaxf(sm[0], sm[1]), fmaxf(sm[2], sm[3]));

  float s = 0.f;
  #pragma unroll
  for (int i = 0; i < 4; ++i) {
    v[i].x = expf(v[i].x - m); v[i].y = expf(v[i].y - m);
    v[i].z = expf(v[i].z - m); v[i].w = expf(v[i].w - m);
    s += v[i].x + v[i].y + v[i].z + v[i].w;
  }
  #pragma unroll
  for (int o = 32; o >= 1; o >>= 1) s += __shfl_xor(s, o);
  __shared__ float ss[4];
  if ((t & 63) == 0) ss[t >> 6] = s;
  __syncthreads();
  s = ss[0] + ss[1] + ss[2] + ss[3];
  const float inv = 1.0f / s;

  #pragma unroll
  for (int i = 0; i < 4; ++i) {
    v[i].x *= inv; v[i].y *= inv; v[i].z *= inv; v[i].w *= inv;
    *(float4*)(pa + t * 4 + i * 1024) = v[i];
  }
}

// ---------------------------------------------------------------------------
// K4: partial xattn[b,n,c] = sum_{j in tile} attn[b,n,j] * x[b,c,j]
// grid (16, B_), block 256, thread owns channel c.
// Single-buffer LDS x staging (33 KB -> 4 blocks/CU; occupancy > pipelining,
// see R4 regression). Inner loop in 4-j groups: attn via wave-uniform
// s_load_dwordx4 (scalar pipe), x via ds_read (pitch 33: 2-way = free).
// ---------------------------------------------------------------------------
#define BJ_  256
#define BJS_ 32
#define XPITCH_ 33
__global__ __launch_bounds__(256) void k_xattn(
    const float* __restrict__ x, const float* __restrict__ attn,
    float* __restrict__ part) {
  const int jt = blockIdx.x;
  const int b  = blockIdx.y;
  const int j0 = jt * BJ_;
  const int t  = threadIdx.x;
  __shared__ float xs[C_ * XPITCH_];   // 33 KB

  const float* xb = x + (size_t)b * C_ * T_;
  const float* ab = attn + (size_t)b * NH_ * T_ + j0;  // wave-uniform base

  float acc[NH_];
  #pragma unroll
  for (int n = 0; n < NH_; ++n) acc[n] = 0.f;

  const int cr = t >> 3;          // 0..31
  const int jc = (t & 7) * 4;     // 0,4,...,28

  for (int sIt = 0; sIt < BJ_ / BJS_; ++sIt) {
    const int js = sIt * BJS_;
    __syncthreads();  // protect xs from previous stage's readers
    #pragma unroll
    for (int p = 0; p < 8; ++p) {
      const int c = cr + p * 32;
      float4 vv = *(const float4*)(xb + (size_t)c * T_ + j0 + js + jc);
      float* dst = &xs[c * XPITCH_ + jc];
      dst[0] = vv.x; dst[1] = vv.y; dst[2] = vv.z; dst[3] = vv.w;
    }
    __syncthreads();
    const float* xr = &xs[t * XPITCH_];
    #pragma unroll
    for (int jg = 0; jg < BJS_ / 4; ++jg) {
      const int j4 = jg * 4;
      const float x0 = xr[j4 + 0], x1 = xr[j4 + 1];
      const float x2 = xr[j4 + 2], x3 = xr[j4 + 3];
      #pragma unroll
      for (int n = 0; n < NH_; ++n) {
        const float4 a = *(const float4*)(ab + (size_t)n * T_ + js + j4);
        acc[n] += a.x * x0 + a.y * x1 + a.z * x2 + a.w * x3;
      }
    }
  }

  float* pb = part + ((size_t)b * 16 + jt) * (NH_ * C_);
  #pragma unroll
  for (int n = 0; n < NH_; ++n) pb[n * C_ + t] = acc[n];
}

// ---------------------------------------------------------------------------
// K5 (merged tail): per batch b —
//   xattn[n,c] = sum_jt part[b,jt,n,c]
//   outv[o]    = bkv[512+o] + Wkv[512+o,:]·xattn[o>>6,:]
//   out[b,m]   = relu(bfc[m] + Wfc[m,:]·outv)
// grid B_, block 512.
// ---------------------------------------------------------------------------
__global__ __launch_bounds__(512) void k_tail(
    const float* __restrict__ part, const float* __restrict__ Wkv,
    const float* __restrict__ bkv, const float* __restrict__ Wfc,
    const float* __restrict__ bfc, float* __restrict__ out) {
  __shared__ float xa_s[NH_ * C_];  // 8 KB
  __shared__ float ov[512];
  const int b = blockIdx.x;
  const int t = threadIdx.x;

  const float* pb = part + (size_t)b * 16 * (NH_ * C_);
  #pragma unroll
  for (int r = 0; r < 4; ++r) {
    const int idx = r * 512 + t;
    float s = 0.f;
    #pragma unroll
    for (int jt = 0; jt < 16; ++jt) s += pb[(size_t)jt * (NH_ * C_) + idx];
    xa_s[idx] = s;
  }
  __syncthreads();

  {
    const int o = t;                       // 0..511
    const float* wrow = Wkv + (size_t)(512 + o) * C_;
    const float* xa = &xa_s[(o >> 6) * C_];  // wave-uniform head -> broadcast
    float s = bkv[512 + o];
    #pragma unroll 8
    for (int c = 0; c < C_; c += 4) {
      float4 w = *(const float4*)(wrow + c);
      s += w.x * xa[c] + w.y * xa[c + 1] + w.z * xa[c + 2] + w.w * xa[c + 3];
    }
    ov[o] = s;
  }
  __syncthreads();

  if (t < 256) {
    const int m = t;
    const float* wrow = Wfc + (size_t)m * 512;
    float s = bfc[m];
    #pragma unroll 8
    for (int o = 0; o < 512; o += 4) {
      float4 w = *(const float4*)(wrow + o);
      s += w.x * ov[o] + w.y * ov[o + 1] + w.z * ov[o + 2] + w.w * ov[o + 3];
    }
    out[(size_t)b * 256 + m] = fmaxf(s, 0.f);
  }
}

// ---------------------------------------------------------------------------
extern "C" void kernel_launch(void* const* d_in, const int* in_sizes, int n_in,
                              void* d_out, int out_size, void* d_ws, size_t ws_size,
                              hipStream_t stream) {
  const float* x     = (const float*)d_in[0];
  const float* query = (const float*)d_in[1];
  const float* Wkv   = (const float*)d_in[2];
  const float* bkv   = (const float*)d_in[3];
  const float* Wq    = (const float*)d_in[4];
  const float* bq    = (const float*)d_in[5];
  const float* Wfc   = (const float*)d_in[6];
  const float* bfc   = (const float*)d_in[7];
  float* out = (float*)d_out;
  float* ws  = (float*)d_ws;

  float* qWt    = ws;                  // 65536
  float* qb     = ws + 65536;          // 256 (pad to 512)
  float* lgpart = ws + 66048;          // 2097152
  float* attn   = ws + 2163200;        // 1048576
  float* part   = ws + 3211776;        // 1048576

  k_prep   <<<dim3(NH_, B_),   256, 0, stream>>>(query, Wkv, bkv, Wq, bq, qWt, qb);
  k_logits <<<dim3(8, 2, B_),  128, 0, stream>>>(x, qWt, qb, lgpart);
  k_softmax<<<B_ * NH_,        256, 0, stream>>>(lgpart, attn);
  k_xattn  <<<dim3(16, B_),    256, 0, stream>>>(x, attn, part);
  k_tail   <<<B_,              512, 0, stream>>>(part, Wkv, bkv, Wfc, bfc, out);
}

// Round 6
// 277.901 us; speedup vs baseline: 1.0928x; 1.0928x over previous
//
#include <hip/hip_runtime.h>
#include <hip/hip_bf16.h>

#define B_     32
#define C_     256
#define T_     4096
#define NH_    8
#define DH_    64

// ---------------------------------------------------------------------------
// K1: fold q-projection into Wkv_k.
//   qW[b,c,n] = scale * sum_d q[b,n,d] * Wkv[n*64+d, c]
//   qb[b,n]   = scale * sum_d q[b,n,d] * bkv[n*64+d]
// grid (NH_, B_) = 256 blocks, block 256.
// ---------------------------------------------------------------------------
__global__ __launch_bounds__(256) void k_prep(
    const float* __restrict__ query, const float* __restrict__ Wkv,
    const float* __restrict__ bkv, const float* __restrict__ Wq,
    const float* __restrict__ bq, float* __restrict__ qWt,
    float* __restrict__ qb) {
  const int n = blockIdx.x;
  const int b = blockIdx.y;
  const int t = threadIdx.x;
  __shared__ float qrow_s[C_];
  __shared__ float psum[4 * 64];
  __shared__ float qsh[64];
  __shared__ float pb_s[64];

  qrow_s[t] = query[(size_t)b * C_ + t];
  __syncthreads();

  {
    const int d = t & 63, ch = t >> 6;
    const float* wrow = Wq + (size_t)(n * DH_ + d) * C_ + ch * 64;
    const float* qr = qrow_s + ch * 64;
    float s = 0.f;
    #pragma unroll
    for (int c = 0; c < 64; c += 4) {
      float4 w = *(const float4*)(wrow + c);
      s += w.x * qr[c] + w.y * qr[c + 1] + w.z * qr[c + 2] + w.w * qr[c + 3];
    }
    psum[ch * 64 + d] = s;
  }
  __syncthreads();
  if (t < 64)
    qsh[t] = bq[n * DH_ + t] + psum[t] + psum[64 + t] + psum[128 + t] + psum[192 + t];
  __syncthreads();

  const float scale = 0.125f;
  {
    const float* wk = Wkv + (size_t)(n * DH_) * C_ + t;
    float acc = 0.f;
    #pragma unroll 8
    for (int dd = 0; dd < DH_; ++dd) acc += qsh[dd] * wk[(size_t)dd * C_];
    qWt[((size_t)b * C_ + t) * NH_ + n] = acc * scale;
  }
  if (t < 64) pb_s[t] = qsh[t] * bkv[n * DH_ + t];
  __syncthreads();
  if (t == 0) {
    float s = 0.f;
    #pragma unroll 8
    for (int dd = 0; dd < 64; ++dd) s += pb_s[dd];
    qb[b * NH_ + n] = s * scale;
  }
}

// ---------------------------------------------------------------------------
// K2: partial logits over a c-half (R3-measured-best config):
//   lgpart[half,b,n,j] = sum_{c in half} qW[b,c,n] * x[b,c,j]  (+qb if half 0)
// grid (8, 2, B_) = 512 blocks (2/CU, 8 waves/CU), block 256, 2 j/thread
// (float2), 8-deep load prefetch.
// ---------------------------------------------------------------------------
__global__ __launch_bounds__(256) void k_logits(
    const float* __restrict__ x, const float* __restrict__ qWt,
    const float* __restrict__ qbv, float* __restrict__ lgpart) {
  const int half = blockIdx.y;
  const int b = blockIdx.z;
  const int t = threadIdx.x;
  const int j = blockIdx.x * 512 + t * 2;
  __shared__ float qws[128 * NH_];  // 4 KB, [c_local][n]

  {
    const float4 v = *(const float4*)(qWt + (size_t)b * (C_ * NH_) + half * 1024 + t * 4);
    *(float4*)(qws + t * 4) = v;
  }
  __syncthreads();

  const float* xb = x + ((size_t)b * C_ + half * 128) * T_ + j;
  const float* qb = qbv + b * NH_;

  float acc0[NH_], acc1[NH_];
  #pragma unroll
  for (int n = 0; n < NH_; ++n) {
    const float init = half ? 0.f : qb[n];
    acc0[n] = init; acc1[n] = init;
  }

  for (int c0 = 0; c0 < 128; c0 += 8) {
    float2 xv[8];
    #pragma unroll
    for (int cc = 0; cc < 8; ++cc)
      xv[cc] = *(const float2*)(xb + (size_t)(c0 + cc) * T_);
    #pragma unroll
    for (int cc = 0; cc < 8; ++cc) {
      const float4 w0 = *(const float4*)(qws + (c0 + cc) * 8);
      const float4 w1 = *(const float4*)(qws + (c0 + cc) * 8 + 4);
      acc0[0] += w0.x * xv[cc].x; acc1[0] += w0.x * xv[cc].y;
      acc0[1] += w0.y * xv[cc].x; acc1[1] += w0.y * xv[cc].y;
      acc0[2] += w0.z * xv[cc].x; acc1[2] += w0.z * xv[cc].y;
      acc0[3] += w0.w * xv[cc].x; acc1[3] += w0.w * xv[cc].y;
      acc0[4] += w1.x * xv[cc].x; acc1[4] += w1.x * xv[cc].y;
      acc0[5] += w1.y * xv[cc].x; acc1[5] += w1.y * xv[cc].y;
      acc0[6] += w1.z * xv[cc].x; acc1[6] += w1.z * xv[cc].y;
      acc0[7] += w1.w * xv[cc].x; acc1[7] += w1.w * xv[cc].y;
    }
  }

  float* lg = lgpart + (((size_t)half * B_ + b) * NH_) * T_ + j;
  #pragma unroll
  for (int n = 0; n < NH_; ++n) {
    float2 o; o.x = acc0[n]; o.y = acc1[n];
    *(float2*)(lg + (size_t)n * T_) = o;
  }
}

// ---------------------------------------------------------------------------
// K3: attn[row,j] = softmax_j(lg0[row,j] + lg1[row,j]); grid 256, block 256.
// ---------------------------------------------------------------------------
__global__ __launch_bounds__(256) void k_softmax(
    const float* __restrict__ lgpart, float* __restrict__ attn) {
  const size_t row = blockIdx.x;  // b*NH + n
  const float* p0 = lgpart + row * T_;
  const float* p1 = lgpart + ((size_t)B_ * NH_ + row) * T_;
  float* pa = attn + row * T_;
  const int t = threadIdx.x;
  float4 v[4];
  #pragma unroll
  for (int i = 0; i < 4; ++i) {
    float4 a = *(const float4*)(p0 + t * 4 + i * 1024);
    float4 c = *(const float4*)(p1 + t * 4 + i * 1024);
    v[i].x = a.x + c.x; v[i].y = a.y + c.y; v[i].z = a.z + c.z; v[i].w = a.w + c.w;
  }

  float m = -3.4e38f;
  #pragma unroll
  for (int i = 0; i < 4; ++i)
    m = fmaxf(m, fmaxf(fmaxf(v[i].x, v[i].y), fmaxf(v[i].z, v[i].w)));
  #pragma unroll
  for (int o = 32; o >= 1; o >>= 1) m = fmaxf(m, __shfl_xor(m, o));
  __shared__ float sm[4];
  if ((t & 63) == 0) sm[t >> 6] = m;
  __syncthreads();
  m = fmaxf(fmaxf(sm[0], sm[1]), fmaxf(sm[2], sm[3]));

  float s = 0.f;
  #pragma unroll
  for (int i = 0; i < 4; ++i) {
    v[i].x = expf(v[i].x - m); v[i].y = expf(v[i].y - m);
    v[i].z = expf(v[i].z - m); v[i].w = expf(v[i].w - m);
    s += v[i].x + v[i].y + v[i].z + v[i].w;
  }
  #pragma unroll
  for (int o = 32; o >= 1; o >>= 1) s += __shfl_xor(s, o);
  __shared__ float ss[4];
  if ((t & 63) == 0) ss[t >> 6] = s;
  __syncthreads();
  s = ss[0] + ss[1] + ss[2] + ss[3];
  const float inv = 1.0f / s;

  #pragma unroll
  for (int i = 0; i < 4; ++i) {
    v[i].x *= inv; v[i].y *= inv; v[i].z *= inv; v[i].w *= inv;
    *(float4*)(pa + t * 4 + i * 1024) = v[i];
  }
}

// ---------------------------------------------------------------------------
// K4: partial xattn[b,n,c] = sum_{j in tile} attn[b,n,j] * x[b,c,j]
// grid (16, B_), block 256, thread owns channel c.  (R3-measured-best config:
// single-buffer 33 KB staging, per-j wave-uniform scalar attn reads.)
// ---------------------------------------------------------------------------
#define BJ_  256
#define BJS_ 32
#define XPITCH_ 33
__global__ __launch_bounds__(256) void k_xattn(
    const float* __restrict__ x, const float* __restrict__ attn,
    float* __restrict__ part) {
  const int jt = blockIdx.x;
  const int b  = blockIdx.y;
  const int j0 = jt * BJ_;
  const int t  = threadIdx.x;
  __shared__ float xs[C_ * XPITCH_];   // 33 KB

  const float* xb = x + (size_t)b * C_ * T_;
  const float* ab = attn + (size_t)b * NH_ * T_ + j0;  // wave-uniform base

  float acc[NH_];
  #pragma unroll
  for (int n = 0; n < NH_; ++n) acc[n] = 0.f;

  const int cr = t >> 3;          // 0..31
  const int jc = (t & 7) * 4;     // 0,4,...,28

  for (int sIt = 0; sIt < BJ_ / BJS_; ++sIt) {
    const int js = sIt * BJS_;
    __syncthreads();  // protect xs from previous stage's readers
    #pragma unroll
    for (int p = 0; p < 8; ++p) {
      const int c = cr + p * 32;
      float4 vv = *(const float4*)(xb + (size_t)c * T_ + j0 + js + jc);
      float* dst = &xs[c * XPITCH_ + jc];
      dst[0] = vv.x; dst[1] = vv.y; dst[2] = vv.z; dst[3] = vv.w;
    }
    __syncthreads();
    const float* xr = &xs[t * XPITCH_];
    #pragma unroll 4
    for (int jj = 0; jj < BJS_; ++jj) {
      const float xv = xr[jj];
      const int j = js + jj;  // wave-uniform
      #pragma unroll
      for (int n = 0; n < NH_; ++n)
        acc[n] += ab[(size_t)n * T_ + j] * xv;  // uniform -> scalar broadcast
    }
  }

  float* pb = part + ((size_t)b * 16 + jt) * (NH_ * C_);
  #pragma unroll
  for (int n = 0; n < NH_; ++n) pb[n * C_ + t] = acc[n];
}

// ---------------------------------------------------------------------------
// K5 (merged tail): per batch b —
//   xattn[n,c] = sum_jt part[b,jt,n,c]
//   outv[o]    = bkv[512+o] + Wkv[512+o,:]·xattn[o>>6,:]
//   out[b,m]   = relu(bfc[m] + Wfc[m,:]·outv)
// grid B_, block 512.
// ---------------------------------------------------------------------------
__global__ __launch_bounds__(512) void k_tail(
    const float* __restrict__ part, const float* __restrict__ Wkv,
    const float* __restrict__ bkv, const float* __restrict__ Wfc,
    const float* __restrict__ bfc, float* __restrict__ out) {
  __shared__ float xa_s[NH_ * C_];  // 8 KB
  __shared__ float ov[512];
  const int b = blockIdx.x;
  const int t = threadIdx.x;

  const float* pb = part + (size_t)b * 16 * (NH_ * C_);
  #pragma unroll
  for (int r = 0; r < 4; ++r) {
    const int idx = r * 512 + t;
    float s = 0.f;
    #pragma unroll
    for (int jt = 0; jt < 16; ++jt) s += pb[(size_t)jt * (NH_ * C_) + idx];
    xa_s[idx] = s;
  }
  __syncthreads();

  {
    const int o = t;                         // 0..511
    const float* wrow = Wkv + (size_t)(512 + o) * C_;
    const float* xa = &xa_s[(o >> 6) * C_];  // wave-uniform head -> broadcast
    float s = bkv[512 + o];
    #pragma unroll 8
    for (int c = 0; c < C_; c += 4) {
      float4 w = *(const float4*)(wrow + c);
      s += w.x * xa[c] + w.y * xa[c + 1] + w.z * xa[c + 2] + w.w * xa[c + 3];
    }
    ov[o] = s;
  }
  __syncthreads();

  if (t < 256) {
    const int m = t;
    const float* wrow = Wfc + (size_t)m * 512;
    float s = bfc[m];
    #pragma unroll 8
    for (int o = 0; o < 512; o += 4) {
      float4 w = *(const float4*)(wrow + o);
      s += w.x * ov[o] + w.y * ov[o + 1] + w.z * ov[o + 2] + w.w * ov[o + 3];
    }
    out[(size_t)b * 256 + m] = fmaxf(s, 0.f);
  }
}

// ---------------------------------------------------------------------------
extern "C" void kernel_launch(void* const* d_in, const int* in_sizes, int n_in,
                              void* d_out, int out_size, void* d_ws, size_t ws_size,
                              hipStream_t stream) {
  const float* x     = (const float*)d_in[0];
  const float* query = (const float*)d_in[1];
  const float* Wkv   = (const float*)d_in[2];
  const float* bkv   = (const float*)d_in[3];
  const float* Wq    = (const float*)d_in[4];
  const float* bq    = (const float*)d_in[5];
  const float* Wfc   = (const float*)d_in[6];
  const float* bfc   = (const float*)d_in[7];
  float* out = (float*)d_out;
  float* ws  = (float*)d_ws;

  float* qWt    = ws;                  // 65536
  float* qb     = ws + 65536;          // 256 (pad to 512)
  float* lgpart = ws + 66048;          // 2097152
  float* attn   = ws + 2163200;        // 1048576
  float* part   = ws + 3211776;        // 1048576

  k_prep   <<<dim3(NH_, B_),   256, 0, stream>>>(query, Wkv, bkv, Wq, bq, qWt, qb);
  k_logits <<<dim3(8, 2, B_),  256, 0, stream>>>(x, qWt, qb, lgpart);
  k_softmax<<<B_ * NH_,        256, 0, stream>>>(lgpart, attn);
  k_xattn  <<<dim3(16, B_),    256, 0, stream>>>(x, attn, part);
  k_tail   <<<B_,              512, 0, stream>>>(part, Wkv, bkv, Wfc, bfc, out);
}